// Round 3
// baseline (225.154 us; speedup 1.0000x reference)
//
#include <hip/hip_runtime.h>
#include <hip/hip_bf16.h>
#include <stdint.h>

#define DIM 1024
#define SEQ 2048
#define NB 4
#define HEADS 8
#define HD 128
#define ROWS (NB*SEQ)   // 8192

typedef __attribute__((ext_vector_type(8))) short bf16x8;
typedef __attribute__((ext_vector_type(4))) float f32x4;

static __device__ __forceinline__ unsigned short f2bf(float f){
  union { float f; unsigned int u; } x; x.f = f;
  unsigned int r = x.u + 0x7fffu + ((x.u >> 16) & 1u);
  return (unsigned short)(r >> 16);
}

static __device__ __forceinline__ void gld_lds16(const void* g, void* l){
  __builtin_amdgcn_global_load_lds(
      (const __attribute__((address_space(1))) void*)g,
      (__attribute__((address_space(3))) void*)l,
      16, 0, 0);
}

// ---------------- elementwise cast x -> bf16 ----------------
__global__ void k_cast(const float* __restrict__ src, unsigned short* __restrict__ dst, int n4){
  int i = blockIdx.x * blockDim.x + threadIdx.x;
  if (i >= n4) return;
  const float4 v = reinterpret_cast<const float4*>(src)[i];
  ushort4 o;
  o.x = f2bf(v.x); o.y = f2bf(v.y); o.z = f2bf(v.z); o.w = f2bf(v.w);
  reinterpret_cast<ushort4*>(dst)[i] = o;
}

// ---------------- transpose + cast weight [in][out] -> [out][in] bf16 ----------------
__global__ void k_transpose_cast(const float* __restrict__ W, unsigned short* __restrict__ WT){
  __shared__ float tile[64][65];
  const int tid = threadIdx.x;
  const int bi = blockIdx.y * 64;
  const int bo = blockIdx.x * 64;
  #pragma unroll
  for (int it = 0; it < 16; ++it){
    int f = it*256 + tid;
    int r = f >> 6, c = f & 63;
    tile[r][c] = W[(size_t)(bi + r) * DIM + bo + c];
  }
  __syncthreads();
  #pragma unroll
  for (int it = 0; it < 16; ++it){
    int f = it*256 + tid;
    int r = f >> 6, c = f & 63;
    WT[(size_t)(bo + r) * DIM + bi + c] = f2bf(tile[c][r]);
  }
}

// ---------------- precompute ewb[h][t][s] = (s<=t) ? bf16(exp(w_aft)) : 0 ----------------
__global__ void k_ew(const float* __restrict__ waft, unsigned short* __restrict__ ewb){
  const int t = blockIdx.x;
  const int h = blockIdx.y;
  const float* src = waft + ((size_t)h*SEQ + t) * SEQ;
  unsigned short* dst = ewb + ((size_t)h*SEQ + t) * SEQ;
  const int smax4 = ((t & ~127) + 128) >> 2;
  for (int i = threadIdx.x; i < smax4; i += blockDim.x){
    const float4 w4 = reinterpret_cast<const float4*>(src)[i];
    const int s = i * 4;
    ushort4 o;
    o.x = (s+0 <= t) ? f2bf(__expf(w4.x)) : (unsigned short)0;
    o.y = (s+1 <= t) ? f2bf(__expf(w4.y)) : (unsigned short)0;
    o.z = (s+2 <= t) ? f2bf(__expf(w4.z)) : (unsigned short)0;
    o.w = (s+3 <= t) ? f2bf(__expf(w4.w)) : (unsigned short)0;
    reinterpret_cast<ushort4*>(dst)[i] = o;
  }
}

// ---------------- fused K/V projection GEMM (double-buffered 2-phase) ----------------
__global__ __launch_bounds__(256) void k_proj(
    const unsigned short* __restrict__ xb,
    const unsigned short* __restrict__ wkt,
    const unsigned short* __restrict__ wvt,
    const float* __restrict__ bk,
    const float* __restrict__ bv,
    unsigned short* __restrict__ ekb)
{
  __shared__ unsigned short Al[2][128*64];
  __shared__ unsigned short Bkl[2][128*64];
  __shared__ unsigned short Bvl[2][128*64];
  const int tid  = threadIdx.x;
  const int lane = tid & 63;
  const int wr   = tid >> 7;
  const int wc   = (tid >> 6) & 1;
  const int row0 = blockIdx.x * 128;
  const int col0 = blockIdx.y * 128;

  f32x4 acck[4][4] = {};
  f32x4 accv[4][4] = {};

  // prologue: stage kt=0 into buf 0
  #pragma unroll
  for (int it = 0; it < 4; ++it){
    const int o = it*4096 + tid*16;
    const int r = o >> 7;
    const int k = (o & 127) >> 1;
    gld_lds16(xb  + (size_t)(row0 + r)*DIM + k, (char*)&Al[0][0]  + o);
    gld_lds16(wkt + (size_t)(col0 + r)*DIM + k, (char*)&Bkl[0][0] + o);
    gld_lds16(wvt + (size_t)(col0 + r)*DIM + k, (char*)&Bvl[0][0] + o);
  }
  __syncthreads();

  int cur = 0;
  for (int kt = 0; kt < DIM/64; ++kt){
    if (kt + 1 < DIM/64){
      const int kbase = (kt + 1) * 64;
      #pragma unroll
      for (int it = 0; it < 4; ++it){
        const int o = it*4096 + tid*16;
        const int r = o >> 7;
        const int k = (o & 127) >> 1;
        gld_lds16(xb  + (size_t)(row0 + r)*DIM + kbase + k, (char*)&Al[cur^1][0]  + o);
        gld_lds16(wkt + (size_t)(col0 + r)*DIM + kbase + k, (char*)&Bkl[cur^1][0] + o);
        gld_lds16(wvt + (size_t)(col0 + r)*DIM + kbase + k, (char*)&Bvl[cur^1][0] + o);
      }
    }
    #pragma unroll
    for (int ks = 0; ks < 2; ++ks){
      const int k0 = ks*32 + ((lane >> 4) << 3);
      bf16x8 af[4], bkf[4], bvf[4];
      #pragma unroll
      for (int i = 0; i < 4; ++i)
        af[i] = *reinterpret_cast<const bf16x8*>(&Al[cur][(wr*64 + i*16 + (lane&15))*64 + k0]);
      #pragma unroll
      for (int j = 0; j < 4; ++j){
        bkf[j] = *reinterpret_cast<const bf16x8*>(&Bkl[cur][(wc*64 + j*16 + (lane&15))*64 + k0]);
        bvf[j] = *reinterpret_cast<const bf16x8*>(&Bvl[cur][(wc*64 + j*16 + (lane&15))*64 + k0]);
      }
      #pragma unroll
      for (int i = 0; i < 4; ++i)
        #pragma unroll
        for (int j = 0; j < 4; ++j){
          acck[i][j] = __builtin_amdgcn_mfma_f32_16x16x32_bf16(af[i], bkf[j], acck[i][j], 0, 0, 0);
          accv[i][j] = __builtin_amdgcn_mfma_f32_16x16x32_bf16(af[i], bvf[j], accv[i][j], 0, 0, 0);
        }
    }
    __syncthreads();
    cur ^= 1;
  }

  #pragma unroll
  for (int j = 0; j < 4; ++j){
    const int c = col0 + wc*64 + j*16 + (lane & 15);
    const int h = c >> 7;
    const int d = c & 127;
    const float bkc = bk[c];
    const float bvc = bv[c];
    #pragma unroll
    for (int i = 0; i < 4; ++i){
      #pragma unroll
      for (int jj = 0; jj < 4; ++jj){
        const int r = row0 + wr*64 + i*16 + ((lane>>4)<<2) + jj;
        const int n = r >> 11;
        const int s = r & 2047;
        const float kval = acck[i][j][jj] + bkc;
        const float vval = accv[i][j][jj] + bvc;
        const float ek  = __expf(kval);
        const float ekv = ek * vval;
        const size_t idx = ((size_t)h*1024 + n*256 + d) * SEQ + s;
        ekb[idx] = f2bf(ek);
        ekb[idx + (size_t)128*SEQ] = f2bf(ekv);
      }
    }
  }
}

// ---------------- AFT causal core (BN=256: den+num fused, division in epilogue) ----------------
// Block (p, n, h): pairs t-tiles {15-p, p}. Wave (wr,wc): rows wr*64, den cols wc*64, num cols 128+wc*64.
__global__ __launch_bounds__(256) void k_core(
    const unsigned short* __restrict__ ewb,
    const unsigned short* __restrict__ ekb,
    unsigned short* __restrict__ aftb)
{
  __shared__ unsigned short Al[2][128*64];   // ew tile [t][s]   32 KB
  __shared__ unsigned short Bl[2][256*64];   // ek|ekv [c][s]    64 KB
  const int tid  = threadIdx.x;
  const int lane = tid & 63;
  const int wr   = tid >> 7;
  const int wc   = (tid >> 6) & 1;
  const int p = blockIdx.x;
  const int n = blockIdx.y;
  const int h = blockIdx.z;

  const unsigned short* bbase = ekb + ((size_t)h*1024 + n*256) * SEQ;

  #pragma unroll
  for (int half = 0; half < 2; ++half){
    const int tt = half ? p : (15 - p);
    const int t0 = tt * 128;
    const int nst = 2*tt + 2;
    const unsigned short* abase = ewb + ((size_t)h*SEQ + t0) * SEQ;

    f32x4 accd[4][4] = {};
    f32x4 accn[4][4] = {};

    // prologue: stage s-tile 0 into buf 0
    #pragma unroll
    for (int it = 0; it < 4; ++it){
      const int o = it*4096 + tid*16;
      const int r = o >> 7;
      const int k = (o & 127) >> 1;
      gld_lds16(abase + (size_t)r*SEQ + k, (char*)&Al[0][0] + o);
    }
    #pragma unroll
    for (int it = 0; it < 8; ++it){
      const int o = it*4096 + tid*16;
      const int r = o >> 7;
      const int k = (o & 127) >> 1;
      gld_lds16(bbase + (size_t)r*SEQ + k, (char*)&Bl[0][0] + o);
    }
    __syncthreads();

    int cur = 0;
    for (int st = 0; st < nst; ++st){
      if (st + 1 < nst){
        const int s0 = (st + 1) * 64;
        #pragma unroll
        for (int it = 0; it < 4; ++it){
          const int o = it*4096 + tid*16;
          const int r = o >> 7;
          const int k = (o & 127) >> 1;
          gld_lds16(abase + (size_t)r*SEQ + s0 + k, (char*)&Al[cur^1][0] + o);
        }
        #pragma unroll
        for (int it = 0; it < 8; ++it){
          const int o = it*4096 + tid*16;
          const int r = o >> 7;
          const int k = (o & 127) >> 1;
          gld_lds16(bbase + (size_t)r*SEQ + s0 + k, (char*)&Bl[cur^1][0] + o);
        }
      }
      #pragma unroll
      for (int ks = 0; ks < 2; ++ks){
        const int k0 = ks*32 + ((lane >> 4) << 3);
        bf16x8 af[4], bd[4], bn[4];
        #pragma unroll
        for (int i = 0; i < 4; ++i)
          af[i] = *reinterpret_cast<const bf16x8*>(&Al[cur][(wr*64 + i*16 + (lane&15))*64 + k0]);
        #pragma unroll
        for (int j = 0; j < 4; ++j){
          bd[j] = *reinterpret_cast<const bf16x8*>(&Bl[cur][(wc*64 + j*16 + (lane&15))*64 + k0]);
          bn[j] = *reinterpret_cast<const bf16x8*>(&Bl[cur][(128*64) + (wc*64 + j*16 + (lane&15))*64 + k0]);
        }
        #pragma unroll
        for (int i = 0; i < 4; ++i)
          #pragma unroll
          for (int j = 0; j < 4; ++j){
            accd[i][j] = __builtin_amdgcn_mfma_f32_16x16x32_bf16(af[i], bd[j], accd[i][j], 0, 0, 0);
            accn[i][j] = __builtin_amdgcn_mfma_f32_16x16x32_bf16(af[i], bn[j], accn[i][j], 0, 0, 0);
          }
      }
      __syncthreads();
      cur ^= 1;
    }

    #pragma unroll
    for (int j = 0; j < 4; ++j){
      const int d = wc*64 + j*16 + (lane & 15);
      #pragma unroll
      for (int i = 0; i < 4; ++i){
        #pragma unroll
        for (int jj = 0; jj < 4; ++jj){
          const int t = t0 + wr*64 + i*16 + ((lane>>4)<<2) + jj;
          aftb[((size_t)n*SEQ + t)*DIM + h*HD + d] = f2bf(accn[i][j][jj] / accd[i][j][jj]);
        }
      }
    }
  }
}

// ---------------- output projection GEMM + bias (double-buffered 2-phase) ----------------
__global__ __launch_bounds__(256) void k_out(
    const unsigned short* __restrict__ aftb,
    const unsigned short* __restrict__ wot,
    const float* __restrict__ bo,
    float* __restrict__ out)
{
  __shared__ unsigned short Al[2][128*64];
  __shared__ unsigned short Bl[2][128*64];
  const int tid  = threadIdx.x;
  const int lane = tid & 63;
  const int wr   = tid >> 7;
  const int wc   = (tid >> 6) & 1;
  const int row0 = blockIdx.x * 128;
  const int col0 = blockIdx.y * 128;

  f32x4 acc[4][4] = {};

  #pragma unroll
  for (int it = 0; it < 4; ++it){
    const int o = it*4096 + tid*16;
    const int r = o >> 7;
    const int k = (o & 127) >> 1;
    gld_lds16(aftb + (size_t)(row0 + r)*DIM + k, (char*)&Al[0][0] + o);
    gld_lds16(wot  + (size_t)(col0 + r)*DIM + k, (char*)&Bl[0][0] + o);
  }
  __syncthreads();

  int cur = 0;
  for (int kt = 0; kt < DIM/64; ++kt){
    if (kt + 1 < DIM/64){
      const int kbase = (kt + 1) * 64;
      #pragma unroll
      for (int it = 0; it < 4; ++it){
        const int o = it*4096 + tid*16;
        const int r = o >> 7;
        const int k = (o & 127) >> 1;
        gld_lds16(aftb + (size_t)(row0 + r)*DIM + kbase + k, (char*)&Al[cur^1][0] + o);
        gld_lds16(wot  + (size_t)(col0 + r)*DIM + kbase + k, (char*)&Bl[cur^1][0] + o);
      }
    }
    #pragma unroll
    for (int ks = 0; ks < 2; ++ks){
      const int k0 = ks*32 + ((lane >> 4) << 3);
      bf16x8 af[4], bfr[4];
      #pragma unroll
      for (int i = 0; i < 4; ++i)
        af[i] = *reinterpret_cast<const bf16x8*>(&Al[cur][(wr*64 + i*16 + (lane&15))*64 + k0]);
      #pragma unroll
      for (int j = 0; j < 4; ++j)
        bfr[j] = *reinterpret_cast<const bf16x8*>(&Bl[cur][(wc*64 + j*16 + (lane&15))*64 + k0]);
      #pragma unroll
      for (int i = 0; i < 4; ++i)
        #pragma unroll
        for (int j = 0; j < 4; ++j)
          acc[i][j] = __builtin_amdgcn_mfma_f32_16x16x32_bf16(af[i], bfr[j], acc[i][j], 0, 0, 0);
    }
    __syncthreads();
    cur ^= 1;
  }

  #pragma unroll
  for (int j = 0; j < 4; ++j){
    const int c = col0 + wc*64 + j*16 + (lane & 15);
    const float boc = bo[c];
    #pragma unroll
    for (int i = 0; i < 4; ++i){
      #pragma unroll
      for (int jj = 0; jj < 4; ++jj){
        const int r = row0 + wr*64 + i*16 + ((lane>>4)<<2) + jj;
        out[(size_t)r*DIM + c] = acc[i][j][jj] + boc;
      }
    }
  }
}

extern "C" void kernel_launch(void* const* d_in, const int* in_sizes, int n_in,
                              void* d_out, int out_size, void* d_ws, size_t ws_size,
                              hipStream_t stream){
  const float* x    = (const float*)d_in[0];
  const float* Wk   = (const float*)d_in[1];
  const float* bk   = (const float*)d_in[2];
  const float* Wv   = (const float*)d_in[3];
  const float* bv   = (const float*)d_in[4];
  const float* waft = (const float*)d_in[5];
  const float* Wo   = (const float*)d_in[6];
  const float* bo   = (const float*)d_in[7];
  float* out = (float*)d_out;

  char* w = (char*)d_ws;
  unsigned short* xb   = (unsigned short*)w; w += (size_t)ROWS*DIM*2;       // 16 MB
  unsigned short* wkt  = (unsigned short*)w; w += (size_t)DIM*DIM*2;        // 2 MB
  unsigned short* wvt  = (unsigned short*)w; w += (size_t)DIM*DIM*2;        // 2 MB
  unsigned short* wot  = (unsigned short*)w; w += (size_t)DIM*DIM*2;        // 2 MB
  unsigned short* ekb  = (unsigned short*)w; w += (size_t)HEADS*1024*SEQ*2; // 32 MB
  unsigned short* aftb = (unsigned short*)w; w += (size_t)ROWS*DIM*2;       // 16 MB
  unsigned short* ewb  = (unsigned short*)w; w += (size_t)HEADS*SEQ*SEQ*2;  // 64 MB

  k_cast<<<ROWS*DIM/4/256, 256, 0, stream>>>(x, xb, ROWS*DIM/4);
  k_transpose_cast<<<dim3(16,16), 256, 0, stream>>>(Wk, wkt);
  k_transpose_cast<<<dim3(16,16), 256, 0, stream>>>(Wv, wvt);
  k_transpose_cast<<<dim3(16,16), 256, 0, stream>>>(Wo, wot);
  k_ew<<<dim3(SEQ, HEADS), 256, 0, stream>>>(waft, ewb);
  k_proj<<<dim3(64, 8), 256, 0, stream>>>(xb, wkt, wvt, bk, bv, ekb);
  k_core<<<dim3(8, NB, HEADS), 256, 0, stream>>>(ewb, ekb, aftb);
  k_out<<<dim3(64, 8), 256, 0, stream>>>(aftb, wot, bo, out);
}

// Round 4
// 193.116 us; speedup vs baseline: 1.1659x; 1.1659x over previous
//
#include <hip/hip_runtime.h>
#include <hip/hip_bf16.h>
#include <stdint.h>

#define DIM 1024
#define SEQ 2048
#define NB 4
#define HEADS 8
#define HD 128
#define ROWS (NB*SEQ)   // 8192

typedef __attribute__((ext_vector_type(8))) short bf16x8;
typedef __attribute__((ext_vector_type(4))) float f32x4;

static __device__ __forceinline__ unsigned short f2bf(float f){
  union { float f; unsigned int u; } x; x.f = f;
  unsigned int r = x.u + 0x7fffu + ((x.u >> 16) & 1u);
  return (unsigned short)(r >> 16);
}

static __device__ __forceinline__ float bf2f(unsigned short u){
  union { unsigned int u; float f; } x; x.u = ((unsigned int)u) << 16;
  return x.f;
}

static __device__ __forceinline__ void gld_lds16(const void* g, void* l){
  __builtin_amdgcn_global_load_lds(
      (const __attribute__((address_space(1))) void*)g,
      (__attribute__((address_space(3))) void*)l,
      16, 0, 0);
}

// ---------------- elementwise cast x -> bf16 ----------------
__global__ void k_cast(const float* __restrict__ src, unsigned short* __restrict__ dst, int n4){
  int i = blockIdx.x * blockDim.x + threadIdx.x;
  if (i >= n4) return;
  const float4 v = reinterpret_cast<const float4*>(src)[i];
  ushort4 o;
  o.x = f2bf(v.x); o.y = f2bf(v.y); o.z = f2bf(v.z); o.w = f2bf(v.w);
  reinterpret_cast<ushort4*>(dst)[i] = o;
}

// ---------------- transpose + cast weight [in][out] -> [out][in] bf16 ----------------
__global__ void k_transpose_cast(const float* __restrict__ W, unsigned short* __restrict__ WT){
  __shared__ float tile[64][65];
  const int tid = threadIdx.x;
  const int bi = blockIdx.y * 64;
  const int bo = blockIdx.x * 64;
  #pragma unroll
  for (int it = 0; it < 16; ++it){
    int f = it*256 + tid;
    int r = f >> 6, c = f & 63;
    tile[r][c] = W[(size_t)(bi + r) * DIM + bo + c];
  }
  __syncthreads();
  #pragma unroll
  for (int it = 0; it < 16; ++it){
    int f = it*256 + tid;
    int r = f >> 6, c = f & 63;
    WT[(size_t)(bo + r) * DIM + bi + c] = f2bf(tile[c][r]);
  }
}

// ---------------- precompute ewb[h][t][s] = (s<=t) ? bf16(exp(w_aft)) : 0 ----------------
__global__ void k_ew(const float* __restrict__ waft, unsigned short* __restrict__ ewb){
  const int t = blockIdx.x;
  const int h = blockIdx.y;
  const float* src = waft + ((size_t)h*SEQ + t) * SEQ;
  unsigned short* dst = ewb + ((size_t)h*SEQ + t) * SEQ;
  const int smax4 = ((t & ~127) + 128) >> 2;
  for (int i = threadIdx.x; i < smax4; i += blockDim.x){
    const float4 w4 = reinterpret_cast<const float4*>(src)[i];
    const int s = i * 4;
    ushort4 o;
    o.x = (s+0 <= t) ? f2bf(__expf(w4.x)) : (unsigned short)0;
    o.y = (s+1 <= t) ? f2bf(__expf(w4.y)) : (unsigned short)0;
    o.z = (s+2 <= t) ? f2bf(__expf(w4.z)) : (unsigned short)0;
    o.w = (s+3 <= t) ? f2bf(__expf(w4.w)) : (unsigned short)0;
    reinterpret_cast<ushort4*>(dst)[i] = o;
  }
}

// ---------------- fused K/V projection GEMM (BK=32, dbuf, 48 KB -> 2 blocks/CU) ----------------
__global__ __launch_bounds__(256) void k_proj(
    const unsigned short* __restrict__ xb,
    const unsigned short* __restrict__ wkt,
    const unsigned short* __restrict__ wvt,
    const float* __restrict__ bk,
    const float* __restrict__ bv,
    unsigned short* __restrict__ ekb)
{
  __shared__ unsigned short Al[2][128*32];
  __shared__ unsigned short Bkl[2][128*32];
  __shared__ unsigned short Bvl[2][128*32];
  const int tid  = threadIdx.x;
  const int lane = tid & 63;
  const int wr   = tid >> 7;
  const int wc   = (tid >> 6) & 1;
  const int row0 = blockIdx.x * 128;
  const int col0 = blockIdx.y * 128;

  f32x4 acck[4][4] = {};
  f32x4 accv[4][4] = {};

  // prologue: stage kt=0 into buf 0
  #pragma unroll
  for (int it = 0; it < 2; ++it){
    const int o = it*4096 + tid*16;
    const int r = o >> 6;              // 64 B per row (32 bf16)
    const int k = (o & 63) >> 1;
    gld_lds16(xb  + (size_t)(row0 + r)*DIM + k, (char*)&Al[0][0]  + o);
    gld_lds16(wkt + (size_t)(col0 + r)*DIM + k, (char*)&Bkl[0][0] + o);
    gld_lds16(wvt + (size_t)(col0 + r)*DIM + k, (char*)&Bvl[0][0] + o);
  }
  __syncthreads();

  int cur = 0;
  for (int kt = 0; kt < DIM/32; ++kt){
    if (kt + 1 < DIM/32){
      const int kbase = (kt + 1) * 32;
      #pragma unroll
      for (int it = 0; it < 2; ++it){
        const int o = it*4096 + tid*16;
        const int r = o >> 6;
        const int k = (o & 63) >> 1;
        gld_lds16(xb  + (size_t)(row0 + r)*DIM + kbase + k, (char*)&Al[cur^1][0]  + o);
        gld_lds16(wkt + (size_t)(col0 + r)*DIM + kbase + k, (char*)&Bkl[cur^1][0] + o);
        gld_lds16(wvt + (size_t)(col0 + r)*DIM + kbase + k, (char*)&Bvl[cur^1][0] + o);
      }
    }
    const int k0 = (lane >> 4) << 3;
    bf16x8 af[4], bkf[4], bvf[4];
    #pragma unroll
    for (int i = 0; i < 4; ++i)
      af[i] = *reinterpret_cast<const bf16x8*>(&Al[cur][(wr*64 + i*16 + (lane&15))*32 + k0]);
    #pragma unroll
    for (int j = 0; j < 4; ++j){
      bkf[j] = *reinterpret_cast<const bf16x8*>(&Bkl[cur][(wc*64 + j*16 + (lane&15))*32 + k0]);
      bvf[j] = *reinterpret_cast<const bf16x8*>(&Bvl[cur][(wc*64 + j*16 + (lane&15))*32 + k0]);
    }
    #pragma unroll
    for (int i = 0; i < 4; ++i)
      #pragma unroll
      for (int j = 0; j < 4; ++j){
        acck[i][j] = __builtin_amdgcn_mfma_f32_16x16x32_bf16(af[i], bkf[j], acck[i][j], 0, 0, 0);
        accv[i][j] = __builtin_amdgcn_mfma_f32_16x16x32_bf16(af[i], bvf[j], accv[i][j], 0, 0, 0);
      }
    __syncthreads();
    cur ^= 1;
  }

  #pragma unroll
  for (int j = 0; j < 4; ++j){
    const int c = col0 + wc*64 + j*16 + (lane & 15);
    const int h = c >> 7;
    const int d = c & 127;
    const float bkc = bk[c];
    const float bvc = bv[c];
    #pragma unroll
    for (int i = 0; i < 4; ++i){
      #pragma unroll
      for (int jj = 0; jj < 4; ++jj){
        const int r = row0 + wr*64 + i*16 + ((lane>>4)<<2) + jj;
        const int n = r >> 11;
        const int s = r & 2047;
        const float kval = acck[i][j][jj] + bkc;
        const float vval = accv[i][j][jj] + bvc;
        const float ek  = __expf(kval);
        const float ekv = ek * vval;
        const size_t idx = ((size_t)h*1024 + n*256 + d) * SEQ + s;
        ekb[idx] = f2bf(ek);
        ekb[idx + (size_t)128*SEQ] = f2bf(ekv);
      }
    }
  }
}

// ---------------- AFT causal core (ch-split, triangle-paired, dbuf, 64 KB -> 2 blocks/CU) ----------
// Block (bx, n, h): p = bx>>1 pairs t-tiles {15-p, p}; ch = bx&1 selects den (0) / num (1).
// Every block does exactly 34 K-steps.
__global__ __launch_bounds__(256) void k_core(
    const unsigned short* __restrict__ ewb,
    const unsigned short* __restrict__ ekb,
    unsigned short* __restrict__ dens,
    unsigned short* __restrict__ nums)
{
  __shared__ unsigned short Al[2][128*64];
  __shared__ unsigned short Bl[2][128*64];
  const int tid  = threadIdx.x;
  const int lane = tid & 63;
  const int wr   = tid >> 7;
  const int wc   = (tid >> 6) & 1;
  const int p  = blockIdx.x >> 1;
  const int ch = blockIdx.x & 1;
  const int n  = blockIdx.y;
  const int h  = blockIdx.z;

  const unsigned short* bbase = ekb + ((size_t)h*1024 + n*256 + ch*128) * SEQ;
  unsigned short* const outp = ch ? nums : dens;

  #pragma unroll
  for (int half = 0; half < 2; ++half){
    const int tt = half ? p : (15 - p);
    const int t0 = tt * 128;
    const int nst = 2*tt + 2;
    const unsigned short* abase = ewb + ((size_t)h*SEQ + t0) * SEQ;

    f32x4 acc[4][4] = {};

    // prologue: stage s-tile 0 into buf 0
    #pragma unroll
    for (int it = 0; it < 4; ++it){
      const int o = it*4096 + tid*16;
      const int r = o >> 7;
      const int k = (o & 127) >> 1;
      gld_lds16(abase + (size_t)r*SEQ + k, (char*)&Al[0][0] + o);
      gld_lds16(bbase + (size_t)r*SEQ + k, (char*)&Bl[0][0] + o);
    }
    __syncthreads();

    int cur = 0;
    for (int st = 0; st < nst; ++st){
      if (st + 1 < nst){
        const int s0 = (st + 1) * 64;
        #pragma unroll
        for (int it = 0; it < 4; ++it){
          const int o = it*4096 + tid*16;
          const int r = o >> 7;
          const int k = (o & 127) >> 1;
          gld_lds16(abase + (size_t)r*SEQ + s0 + k, (char*)&Al[cur^1][0] + o);
          gld_lds16(bbase + (size_t)r*SEQ + s0 + k, (char*)&Bl[cur^1][0] + o);
        }
      }
      #pragma unroll
      for (int ks = 0; ks < 2; ++ks){
        const int k0 = ks*32 + ((lane >> 4) << 3);
        bf16x8 af[4], bfr[4];
        #pragma unroll
        for (int i = 0; i < 4; ++i)
          af[i] = *reinterpret_cast<const bf16x8*>(&Al[cur][(wr*64 + i*16 + (lane&15))*64 + k0]);
        #pragma unroll
        for (int j = 0; j < 4; ++j)
          bfr[j] = *reinterpret_cast<const bf16x8*>(&Bl[cur][(wc*64 + j*16 + (lane&15))*64 + k0]);
        #pragma unroll
        for (int i = 0; i < 4; ++i)
          #pragma unroll
          for (int j = 0; j < 4; ++j)
            acc[i][j] = __builtin_amdgcn_mfma_f32_16x16x32_bf16(af[i], bfr[j], acc[i][j], 0, 0, 0);
      }
      __syncthreads();
      cur ^= 1;
    }

    #pragma unroll
    for (int j = 0; j < 4; ++j){
      const int d = wc*64 + j*16 + (lane & 15);
      #pragma unroll
      for (int i = 0; i < 4; ++i){
        #pragma unroll
        for (int jj = 0; jj < 4; ++jj){
          const int t = t0 + wr*64 + i*16 + ((lane>>4)<<2) + jj;
          outp[((size_t)n*SEQ + t)*DIM + h*HD + d] = f2bf(acc[i][j][jj]);
        }
      }
    }
    __syncthreads();
  }
}

// ---------------- aft = num/den (bf16 in), cast bf16 ----------------
__global__ void k_div(const unsigned short* __restrict__ nums, const unsigned short* __restrict__ dens,
                      unsigned short* __restrict__ aftb, int n8){
  int i = blockIdx.x * blockDim.x + threadIdx.x;
  if (i >= n8) return;
  ushort4 nu0 = reinterpret_cast<const ushort4*>(nums)[2*i];
  ushort4 nu1 = reinterpret_cast<const ushort4*>(nums)[2*i+1];
  ushort4 de0 = reinterpret_cast<const ushort4*>(dens)[2*i];
  ushort4 de1 = reinterpret_cast<const ushort4*>(dens)[2*i+1];
  ushort4 o0, o1;
  o0.x = f2bf(bf2f(nu0.x)/bf2f(de0.x)); o0.y = f2bf(bf2f(nu0.y)/bf2f(de0.y));
  o0.z = f2bf(bf2f(nu0.z)/bf2f(de0.z)); o0.w = f2bf(bf2f(nu0.w)/bf2f(de0.w));
  o1.x = f2bf(bf2f(nu1.x)/bf2f(de1.x)); o1.y = f2bf(bf2f(nu1.y)/bf2f(de1.y));
  o1.z = f2bf(bf2f(nu1.z)/bf2f(de1.z)); o1.w = f2bf(bf2f(nu1.w)/bf2f(de1.w));
  reinterpret_cast<ushort4*>(aftb)[2*i]   = o0;
  reinterpret_cast<ushort4*>(aftb)[2*i+1] = o1;
}

// ---------------- output projection GEMM + bias (dbuf, 64 KB -> 2 blocks/CU) ----------------
__global__ __launch_bounds__(256) void k_out(
    const unsigned short* __restrict__ aftb,
    const unsigned short* __restrict__ wot,
    const float* __restrict__ bo,
    float* __restrict__ out)
{
  __shared__ unsigned short Al[2][128*64];
  __shared__ unsigned short Bl[2][128*64];
  const int tid  = threadIdx.x;
  const int lane = tid & 63;
  const int wr   = tid >> 7;
  const int wc   = (tid >> 6) & 1;
  const int row0 = blockIdx.x * 128;
  const int col0 = blockIdx.y * 128;

  f32x4 acc[4][4] = {};

  #pragma unroll
  for (int it = 0; it < 4; ++it){
    const int o = it*4096 + tid*16;
    const int r = o >> 7;
    const int k = (o & 127) >> 1;
    gld_lds16(aftb + (size_t)(row0 + r)*DIM + k, (char*)&Al[0][0] + o);
    gld_lds16(wot  + (size_t)(col0 + r)*DIM + k, (char*)&Bl[0][0] + o);
  }
  __syncthreads();

  int cur = 0;
  for (int kt = 0; kt < DIM/64; ++kt){
    if (kt + 1 < DIM/64){
      const int kbase = (kt + 1) * 64;
      #pragma unroll
      for (int it = 0; it < 4; ++it){
        const int o = it*4096 + tid*16;
        const int r = o >> 7;
        const int k = (o & 127) >> 1;
        gld_lds16(aftb + (size_t)(row0 + r)*DIM + kbase + k, (char*)&Al[cur^1][0] + o);
        gld_lds16(wot  + (size_t)(col0 + r)*DIM + kbase + k, (char*)&Bl[cur^1][0] + o);
      }
    }
    #pragma unroll
    for (int ks = 0; ks < 2; ++ks){
      const int k0 = ks*32 + ((lane >> 4) << 3);
      bf16x8 af[4], bfr[4];
      #pragma unroll
      for (int i = 0; i < 4; ++i)
        af[i] = *reinterpret_cast<const bf16x8*>(&Al[cur][(wr*64 + i*16 + (lane&15))*64 + k0]);
      #pragma unroll
      for (int j = 0; j < 4; ++j)
        bfr[j] = *reinterpret_cast<const bf16x8*>(&Bl[cur][(wc*64 + j*16 + (lane&15))*64 + k0]);
      #pragma unroll
      for (int i = 0; i < 4; ++i)
        #pragma unroll
        for (int j = 0; j < 4; ++j)
          acc[i][j] = __builtin_amdgcn_mfma_f32_16x16x32_bf16(af[i], bfr[j], acc[i][j], 0, 0, 0);
    }
    __syncthreads();
    cur ^= 1;
  }

  #pragma unroll
  for (int j = 0; j < 4; ++j){
    const int c = col0 + wc*64 + j*16 + (lane & 15);
    const float boc = bo[c];
    #pragma unroll
    for (int i = 0; i < 4; ++i){
      #pragma unroll
      for (int jj = 0; jj < 4; ++jj){
        const int r = row0 + wr*64 + i*16 + ((lane>>4)<<2) + jj;
        out[(size_t)r*DIM + c] = acc[i][j][jj] + boc;
      }
    }
  }
}

extern "C" void kernel_launch(void* const* d_in, const int* in_sizes, int n_in,
                              void* d_out, int out_size, void* d_ws, size_t ws_size,
                              hipStream_t stream){
  const float* x    = (const float*)d_in[0];
  const float* Wk   = (const float*)d_in[1];
  const float* bk   = (const float*)d_in[2];
  const float* Wv   = (const float*)d_in[3];
  const float* bv   = (const float*)d_in[4];
  const float* waft = (const float*)d_in[5];
  const float* Wo   = (const float*)d_in[6];
  const float* bo   = (const float*)d_in[7];
  float* out = (float*)d_out;

  char* w = (char*)d_ws;
  unsigned short* xb   = (unsigned short*)w; w += (size_t)ROWS*DIM*2;       // 16 MB
  unsigned short* wkt  = (unsigned short*)w; w += (size_t)DIM*DIM*2;        // 2 MB
  unsigned short* wvt  = (unsigned short*)w; w += (size_t)DIM*DIM*2;        // 2 MB
  unsigned short* wot  = (unsigned short*)w; w += (size_t)DIM*DIM*2;        // 2 MB
  unsigned short* ekb  = (unsigned short*)w; w += (size_t)HEADS*1024*SEQ*2; // 32 MB
  unsigned short* dens = (unsigned short*)w; w += (size_t)ROWS*DIM*2;       // 16 MB
  unsigned short* nums = (unsigned short*)w; w += (size_t)ROWS*DIM*2;       // 16 MB
  unsigned short* aftb = (unsigned short*)w; w += (size_t)ROWS*DIM*2;       // 16 MB
  unsigned short* ewb  = (unsigned short*)w; w += (size_t)HEADS*SEQ*SEQ*2;  // 64 MB

  k_cast<<<ROWS*DIM/4/256, 256, 0, stream>>>(x, xb, ROWS*DIM/4);
  k_transpose_cast<<<dim3(16,16), 256, 0, stream>>>(Wk, wkt);
  k_transpose_cast<<<dim3(16,16), 256, 0, stream>>>(Wv, wvt);
  k_transpose_cast<<<dim3(16,16), 256, 0, stream>>>(Wo, wot);
  k_ew<<<dim3(SEQ, HEADS), 256, 0, stream>>>(waft, ewb);
  k_proj<<<dim3(64, 8), 256, 0, stream>>>(xb, wkt, wvt, bk, bv, ekb);
  k_core<<<dim3(16, NB, HEADS), 256, 0, stream>>>(ewb, ekb, dens, nums);
  k_div<<<ROWS*DIM/8/256, 256, 0, stream>>>(nums, dens, aftb, ROWS*DIM/8);
  k_out<<<dim3(64, 8), 256, 0, stream>>>(aftb, wot, bo, out);
}

// Round 5
// 192.666 us; speedup vs baseline: 1.1686x; 1.0023x over previous
//
#include <hip/hip_runtime.h>
#include <hip/hip_bf16.h>
#include <stdint.h>

#define DIM 1024
#define SEQ 2048
#define NB 4
#define HEADS 8
#define HD 128
#define ROWS (NB*SEQ)   // 8192

typedef __attribute__((ext_vector_type(8))) short bf16x8;
typedef __attribute__((ext_vector_type(4))) float f32x4;

static __device__ __forceinline__ unsigned short f2bf(float f){
  union { float f; unsigned int u; } x; x.f = f;
  unsigned int r = x.u + 0x7fffu + ((x.u >> 16) & 1u);
  return (unsigned short)(r >> 16);
}

static __device__ __forceinline__ float bf2f(unsigned short u){
  union { unsigned int u; float f; } x; x.u = ((unsigned int)u) << 16;
  return x.f;
}

static __device__ __forceinline__ void gld_lds16(const void* g, void* l){
  __builtin_amdgcn_global_load_lds(
      (const __attribute__((address_space(1))) void*)g,
      (__attribute__((address_space(3))) void*)l,
      16, 0, 0);
}

// ---------------- elementwise cast x -> bf16 ----------------
__global__ void k_cast(const float* __restrict__ src, unsigned short* __restrict__ dst, int n4){
  int i = blockIdx.x * blockDim.x + threadIdx.x;
  if (i >= n4) return;
  const float4 v = reinterpret_cast<const float4*>(src)[i];
  ushort4 o;
  o.x = f2bf(v.x); o.y = f2bf(v.y); o.z = f2bf(v.z); o.w = f2bf(v.w);
  reinterpret_cast<ushort4*>(dst)[i] = o;
}

// ---------------- transpose + cast 3 weights [in][out] -> [out][in] bf16 (z selects) ----------
__global__ void k_transpose_cast(const float* __restrict__ Wk, const float* __restrict__ Wv,
                                 const float* __restrict__ Wo,
                                 unsigned short* __restrict__ Tk, unsigned short* __restrict__ Tv,
                                 unsigned short* __restrict__ To){
  __shared__ float tile[64][65];
  const int z = blockIdx.z;
  const float* W = (z == 0) ? Wk : (z == 1) ? Wv : Wo;
  unsigned short* WT = (z == 0) ? Tk : (z == 1) ? Tv : To;
  const int tid = threadIdx.x;
  const int bi = blockIdx.y * 64;
  const int bo = blockIdx.x * 64;
  #pragma unroll
  for (int it = 0; it < 16; ++it){
    int f = it*256 + tid;
    int r = f >> 6, c = f & 63;
    tile[r][c] = W[(size_t)(bi + r) * DIM + bo + c];
  }
  __syncthreads();
  #pragma unroll
  for (int it = 0; it < 16; ++it){
    int f = it*256 + tid;
    int r = f >> 6, c = f & 63;
    WT[(size_t)(bo + r) * DIM + bi + c] = f2bf(tile[c][r]);
  }
}

// ---------------- precompute ewb[h][t][s] = (s<=t) ? bf16(exp(w_aft)) : 0 ----------------
__global__ void k_ew(const float* __restrict__ waft, unsigned short* __restrict__ ewb){
  const int t = blockIdx.x;
  const int h = blockIdx.y;
  const float* src = waft + ((size_t)h*SEQ + t) * SEQ;
  unsigned short* dst = ewb + ((size_t)h*SEQ + t) * SEQ;
  const int smax4 = ((t & ~127) + 128) >> 2;
  for (int i = threadIdx.x; i < smax4; i += blockDim.x){
    const float4 w4 = reinterpret_cast<const float4*>(src)[i];
    const int s = i * 4;
    ushort4 o;
    o.x = (s+0 <= t) ? f2bf(__expf(w4.x)) : (unsigned short)0;
    o.y = (s+1 <= t) ? f2bf(__expf(w4.y)) : (unsigned short)0;
    o.z = (s+2 <= t) ? f2bf(__expf(w4.z)) : (unsigned short)0;
    o.w = (s+3 <= t) ? f2bf(__expf(w4.w)) : (unsigned short)0;
    reinterpret_cast<ushort4*>(dst)[i] = o;
  }
}

// ---------------- fused K/V projection GEMM (BK=32, dbuf, 48 KB, XCD-swizzled) ----------------
// 1D grid 512. bx=(D&7)*8+(D>>6) row-block, by=(D>>3)&7 col-block.
// XCD = D%8 = bx>>3: each XCD owns 8 consecutive row-blocks; same-bx blocks adjacent.
__global__ __launch_bounds__(256) void k_proj(
    const unsigned short* __restrict__ xb,
    const unsigned short* __restrict__ wkt,
    const unsigned short* __restrict__ wvt,
    const float* __restrict__ bk,
    const float* __restrict__ bv,
    unsigned short* __restrict__ ekb)
{
  __shared__ unsigned short Al[2][128*32];
  __shared__ unsigned short Bkl[2][128*32];
  __shared__ unsigned short Bvl[2][128*32];
  const int tid  = threadIdx.x;
  const int lane = tid & 63;
  const int wr   = tid >> 7;
  const int wc   = (tid >> 6) & 1;
  const int D    = blockIdx.x;
  const int row0 = ((D & 7) * 8 + (D >> 6)) * 128;
  const int col0 = ((D >> 3) & 7) * 128;

  f32x4 acck[4][4] = {};
  f32x4 accv[4][4] = {};

  #pragma unroll
  for (int it = 0; it < 2; ++it){
    const int o = it*4096 + tid*16;
    const int r = o >> 6;
    const int k = (o & 63) >> 1;
    gld_lds16(xb  + (size_t)(row0 + r)*DIM + k, (char*)&Al[0][0]  + o);
    gld_lds16(wkt + (size_t)(col0 + r)*DIM + k, (char*)&Bkl[0][0] + o);
    gld_lds16(wvt + (size_t)(col0 + r)*DIM + k, (char*)&Bvl[0][0] + o);
  }
  __syncthreads();

  int cur = 0;
  for (int kt = 0; kt < DIM/32; ++kt){
    if (kt + 1 < DIM/32){
      const int kbase = (kt + 1) * 32;
      #pragma unroll
      for (int it = 0; it < 2; ++it){
        const int o = it*4096 + tid*16;
        const int r = o >> 6;
        const int k = (o & 63) >> 1;
        gld_lds16(xb  + (size_t)(row0 + r)*DIM + kbase + k, (char*)&Al[cur^1][0]  + o);
        gld_lds16(wkt + (size_t)(col0 + r)*DIM + kbase + k, (char*)&Bkl[cur^1][0] + o);
        gld_lds16(wvt + (size_t)(col0 + r)*DIM + kbase + k, (char*)&Bvl[cur^1][0] + o);
      }
    }
    const int k0 = (lane >> 4) << 3;
    bf16x8 af[4], bkf[4], bvf[4];
    #pragma unroll
    for (int i = 0; i < 4; ++i)
      af[i] = *reinterpret_cast<const bf16x8*>(&Al[cur][(wr*64 + i*16 + (lane&15))*32 + k0]);
    #pragma unroll
    for (int j = 0; j < 4; ++j){
      bkf[j] = *reinterpret_cast<const bf16x8*>(&Bkl[cur][(wc*64 + j*16 + (lane&15))*32 + k0]);
      bvf[j] = *reinterpret_cast<const bf16x8*>(&Bvl[cur][(wc*64 + j*16 + (lane&15))*32 + k0]);
    }
    #pragma unroll
    for (int i = 0; i < 4; ++i)
      #pragma unroll
      for (int j = 0; j < 4; ++j){
        acck[i][j] = __builtin_amdgcn_mfma_f32_16x16x32_bf16(af[i], bkf[j], acck[i][j], 0, 0, 0);
        accv[i][j] = __builtin_amdgcn_mfma_f32_16x16x32_bf16(af[i], bvf[j], accv[i][j], 0, 0, 0);
      }
    __syncthreads();
    cur ^= 1;
  }

  #pragma unroll
  for (int j = 0; j < 4; ++j){
    const int c = col0 + wc*64 + j*16 + (lane & 15);
    const int h = c >> 7;
    const int d = c & 127;
    const float bkc = bk[c];
    const float bvc = bv[c];
    #pragma unroll
    for (int i = 0; i < 4; ++i){
      #pragma unroll
      for (int jj = 0; jj < 4; ++jj){
        const int r = row0 + wr*64 + i*16 + ((lane>>4)<<2) + jj;
        const int n = r >> 11;
        const int s = r & 2047;
        const float kval = acck[i][j][jj] + bkc;
        const float vval = accv[i][j][jj] + bvc;
        const float ek  = __expf(kval);
        const float ekv = ek * vval;
        const size_t idx = ((size_t)h*1024 + n*256 + d) * SEQ + s;
        ekb[idx] = f2bf(ek);
        ekb[idx + (size_t)128*SEQ] = f2bf(ekv);
      }
    }
  }
}

// ---------------- AFT causal core (ch-split, triangle-paired, dbuf, XCD head-local) ----------
// 1D grid 512: h=D&7 (XCD h owns head h), r=D>>3, p=r>>3, n=(r>>1)&3, ch=r&1.
// The 8 sharers (n,ch) of each (h,p) A-panel are temporally adjacent on one XCD.
__global__ __launch_bounds__(256) void k_core(
    const unsigned short* __restrict__ ewb,
    const unsigned short* __restrict__ ekb,
    unsigned short* __restrict__ dens,
    unsigned short* __restrict__ nums)
{
  __shared__ unsigned short Al[2][128*64];
  __shared__ unsigned short Bl[2][128*64];
  const int tid  = threadIdx.x;
  const int lane = tid & 63;
  const int wr   = tid >> 7;
  const int wc   = (tid >> 6) & 1;
  const int D  = blockIdx.x;
  const int h  = D & 7;
  const int r_ = D >> 3;
  const int p  = r_ >> 3;
  const int n  = (r_ >> 1) & 3;
  const int ch = r_ & 1;

  const unsigned short* bbase = ekb + ((size_t)h*1024 + n*256 + ch*128) * SEQ;
  unsigned short* const outp = ch ? nums : dens;

  #pragma unroll
  for (int half = 0; half < 2; ++half){
    const int tt = half ? p : (15 - p);
    const int t0 = tt * 128;
    const int nst = 2*tt + 2;
    const unsigned short* abase = ewb + ((size_t)h*SEQ + t0) * SEQ;

    f32x4 acc[4][4] = {};

    #pragma unroll
    for (int it = 0; it < 4; ++it){
      const int o = it*4096 + tid*16;
      const int r = o >> 7;
      const int k = (o & 127) >> 1;
      gld_lds16(abase + (size_t)r*SEQ + k, (char*)&Al[0][0] + o);
      gld_lds16(bbase + (size_t)r*SEQ + k, (char*)&Bl[0][0] + o);
    }
    __syncthreads();

    int cur = 0;
    for (int st = 0; st < nst; ++st){
      if (st + 1 < nst){
        const int s0 = (st + 1) * 64;
        #pragma unroll
        for (int it = 0; it < 4; ++it){
          const int o = it*4096 + tid*16;
          const int r = o >> 7;
          const int k = (o & 127) >> 1;
          gld_lds16(abase + (size_t)r*SEQ + s0 + k, (char*)&Al[cur^1][0] + o);
          gld_lds16(bbase + (size_t)r*SEQ + s0 + k, (char*)&Bl[cur^1][0] + o);
        }
      }
      #pragma unroll
      for (int ks = 0; ks < 2; ++ks){
        const int k0 = ks*32 + ((lane >> 4) << 3);
        bf16x8 af[4], bfr[4];
        #pragma unroll
        for (int i = 0; i < 4; ++i)
          af[i] = *reinterpret_cast<const bf16x8*>(&Al[cur][(wr*64 + i*16 + (lane&15))*64 + k0]);
        #pragma unroll
        for (int j = 0; j < 4; ++j)
          bfr[j] = *reinterpret_cast<const bf16x8*>(&Bl[cur][(wc*64 + j*16 + (lane&15))*64 + k0]);
        #pragma unroll
        for (int i = 0; i < 4; ++i)
          #pragma unroll
          for (int j = 0; j < 4; ++j)
            acc[i][j] = __builtin_amdgcn_mfma_f32_16x16x32_bf16(af[i], bfr[j], acc[i][j], 0, 0, 0);
      }
      __syncthreads();
      cur ^= 1;
    }

    #pragma unroll
    for (int j = 0; j < 4; ++j){
      const int d = wc*64 + j*16 + (lane & 15);
      #pragma unroll
      for (int i = 0; i < 4; ++i){
        #pragma unroll
        for (int jj = 0; jj < 4; ++jj){
          const int t = t0 + wr*64 + i*16 + ((lane>>4)<<2) + jj;
          outp[((size_t)n*SEQ + t)*DIM + h*HD + d] = f2bf(acc[i][j][jj]);
        }
      }
    }
    __syncthreads();
  }
}

// ---------------- aft = num/den (bf16 in), cast bf16 ----------------
__global__ void k_div(const unsigned short* __restrict__ nums, const unsigned short* __restrict__ dens,
                      unsigned short* __restrict__ aftb, int n8){
  int i = blockIdx.x * blockDim.x + threadIdx.x;
  if (i >= n8) return;
  ushort4 nu0 = reinterpret_cast<const ushort4*>(nums)[2*i];
  ushort4 nu1 = reinterpret_cast<const ushort4*>(nums)[2*i+1];
  ushort4 de0 = reinterpret_cast<const ushort4*>(dens)[2*i];
  ushort4 de1 = reinterpret_cast<const ushort4*>(dens)[2*i+1];
  ushort4 o0, o1;
  o0.x = f2bf(bf2f(nu0.x)/bf2f(de0.x)); o0.y = f2bf(bf2f(nu0.y)/bf2f(de0.y));
  o0.z = f2bf(bf2f(nu0.z)/bf2f(de0.z)); o0.w = f2bf(bf2f(nu0.w)/bf2f(de0.w));
  o1.x = f2bf(bf2f(nu1.x)/bf2f(de1.x)); o1.y = f2bf(bf2f(nu1.y)/bf2f(de1.y));
  o1.z = f2bf(bf2f(nu1.z)/bf2f(de1.z)); o1.w = f2bf(bf2f(nu1.w)/bf2f(de1.w));
  reinterpret_cast<ushort4*>(aftb)[2*i]   = o0;
  reinterpret_cast<ushort4*>(aftb)[2*i+1] = o1;
}

// ---------------- output projection GEMM + bias (dbuf, 64 KB, XCD-swizzled) ----------------
__global__ __launch_bounds__(256) void k_out(
    const unsigned short* __restrict__ aftb,
    const unsigned short* __restrict__ wot,
    const float* __restrict__ bo,
    float* __restrict__ out)
{
  __shared__ unsigned short Al[2][128*64];
  __shared__ unsigned short Bl[2][128*64];
  const int tid  = threadIdx.x;
  const int lane = tid & 63;
  const int wr   = tid >> 7;
  const int wc   = (tid >> 6) & 1;
  const int D    = blockIdx.x;
  const int row0 = ((D & 7) * 8 + (D >> 6)) * 128;
  const int col0 = ((D >> 3) & 7) * 128;

  f32x4 acc[4][4] = {};

  #pragma unroll
  for (int it = 0; it < 4; ++it){
    const int o = it*4096 + tid*16;
    const int r = o >> 7;
    const int k = (o & 127) >> 1;
    gld_lds16(aftb + (size_t)(row0 + r)*DIM + k, (char*)&Al[0][0] + o);
    gld_lds16(wot  + (size_t)(col0 + r)*DIM + k, (char*)&Bl[0][0] + o);
  }
  __syncthreads();

  int cur = 0;
  for (int kt = 0; kt < DIM/64; ++kt){
    if (kt + 1 < DIM/64){
      const int kbase = (kt + 1) * 64;
      #pragma unroll
      for (int it = 0; it < 4; ++it){
        const int o = it*4096 + tid*16;
        const int r = o >> 7;
        const int k = (o & 127) >> 1;
        gld_lds16(aftb + (size_t)(row0 + r)*DIM + kbase + k, (char*)&Al[cur^1][0] + o);
        gld_lds16(wot  + (size_t)(col0 + r)*DIM + kbase + k, (char*)&Bl[cur^1][0] + o);
      }
    }
    #pragma unroll
    for (int ks = 0; ks < 2; ++ks){
      const int k0 = ks*32 + ((lane >> 4) << 3);
      bf16x8 af[4], bfr[4];
      #pragma unroll
      for (int i = 0; i < 4; ++i)
        af[i] = *reinterpret_cast<const bf16x8*>(&Al[cur][(wr*64 + i*16 + (lane&15))*64 + k0]);
      #pragma unroll
      for (int j = 0; j < 4; ++j)
        bfr[j] = *reinterpret_cast<const bf16x8*>(&Bl[cur][(wc*64 + j*16 + (lane&15))*64 + k0]);
      #pragma unroll
      for (int i = 0; i < 4; ++i)
        #pragma unroll
        for (int j = 0; j < 4; ++j)
          acc[i][j] = __builtin_amdgcn_mfma_f32_16x16x32_bf16(af[i], bfr[j], acc[i][j], 0, 0, 0);
    }
    __syncthreads();
    cur ^= 1;
  }

  #pragma unroll
  for (int j = 0; j < 4; ++j){
    const int c = col0 + wc*64 + j*16 + (lane & 15);
    const float boc = bo[c];
    #pragma unroll
    for (int i = 0; i < 4; ++i){
      #pragma unroll
      for (int jj = 0; jj < 4; ++jj){
        const int r = row0 + wr*64 + i*16 + ((lane>>4)<<2) + jj;
        out[(size_t)r*DIM + c] = acc[i][j][jj] + boc;
      }
    }
  }
}

extern "C" void kernel_launch(void* const* d_in, const int* in_sizes, int n_in,
                              void* d_out, int out_size, void* d_ws, size_t ws_size,
                              hipStream_t stream){
  const float* x    = (const float*)d_in[0];
  const float* Wk   = (const float*)d_in[1];
  const float* bk   = (const float*)d_in[2];
  const float* Wv   = (const float*)d_in[3];
  const float* bv   = (const float*)d_in[4];
  const float* waft = (const float*)d_in[5];
  const float* Wo   = (const float*)d_in[6];
  const float* bo   = (const float*)d_in[7];
  float* out = (float*)d_out;

  char* w = (char*)d_ws;
  unsigned short* xb   = (unsigned short*)w; w += (size_t)ROWS*DIM*2;       // 16 MB
  unsigned short* wkt  = (unsigned short*)w; w += (size_t)DIM*DIM*2;        // 2 MB
  unsigned short* wvt  = (unsigned short*)w; w += (size_t)DIM*DIM*2;        // 2 MB
  unsigned short* wot  = (unsigned short*)w; w += (size_t)DIM*DIM*2;        // 2 MB
  unsigned short* ekb  = (unsigned short*)w; w += (size_t)HEADS*1024*SEQ*2; // 32 MB
  unsigned short* dens = (unsigned short*)w; w += (size_t)ROWS*DIM*2;       // 16 MB
  unsigned short* nums = (unsigned short*)w; w += (size_t)ROWS*DIM*2;       // 16 MB
  unsigned short* aftb = (unsigned short*)w; w += (size_t)ROWS*DIM*2;       // 16 MB
  unsigned short* ewb  = (unsigned short*)w; w += (size_t)HEADS*SEQ*SEQ*2;  // 64 MB

  k_cast<<<ROWS*DIM/4/256, 256, 0, stream>>>(x, xb, ROWS*DIM/4);
  k_transpose_cast<<<dim3(16,16,3), 256, 0, stream>>>(Wk, Wv, Wo, wkt, wvt, wot);
  k_ew<<<dim3(SEQ, HEADS), 256, 0, stream>>>(waft, ewb);
  k_proj<<<512, 256, 0, stream>>>(xb, wkt, wvt, bk, bv, ekb);
  k_core<<<512, 256, 0, stream>>>(ewb, ekb, dens, nums);
  k_div<<<ROWS*DIM/8/256, 256, 0, stream>>>(nums, dens, aftb, ROWS*DIM/8);
  k_out<<<512, 256, 0, stream>>>(aftb, wot, bo, out);
}

// Round 6
// 182.269 us; speedup vs baseline: 1.2353x; 1.0570x over previous
//
#include <hip/hip_runtime.h>
#include <hip/hip_bf16.h>
#include <stdint.h>

#define DIM 1024
#define SEQ 2048
#define NB 4
#define HEADS 8
#define HD 128
#define ROWS (NB*SEQ)   // 8192

typedef __attribute__((ext_vector_type(8))) short bf16x8;
typedef __attribute__((ext_vector_type(4))) float f32x4;

#define VMCNT(n) asm volatile("s_waitcnt vmcnt(" #n ")" ::: "memory")
#define SBAR()   __builtin_amdgcn_s_barrier()
#define SCHED0() __builtin_amdgcn_sched_barrier(0)

static __device__ __forceinline__ unsigned short f2bf(float f){
  union { float f; unsigned int u; } x; x.f = f;
  unsigned int r = x.u + 0x7fffu + ((x.u >> 16) & 1u);
  return (unsigned short)(r >> 16);
}

static __device__ __forceinline__ float bf2f(unsigned short u){
  union { unsigned int u; float f; } x; x.u = ((unsigned int)u) << 16;
  return x.f;
}

static __device__ __forceinline__ void gld_lds16(const void* g, void* l){
  __builtin_amdgcn_global_load_lds(
      (const __attribute__((address_space(1))) void*)g,
      (__attribute__((address_space(3))) void*)l,
      16, 0, 0);
}

// ---------------- elementwise cast x -> bf16 ----------------
__global__ void k_cast(const float* __restrict__ src, unsigned short* __restrict__ dst, int n4){
  int i = blockIdx.x * blockDim.x + threadIdx.x;
  if (i >= n4) return;
  const float4 v = reinterpret_cast<const float4*>(src)[i];
  ushort4 o;
  o.x = f2bf(v.x); o.y = f2bf(v.y); o.z = f2bf(v.z); o.w = f2bf(v.w);
  reinterpret_cast<ushort4*>(dst)[i] = o;
}

// ---------------- transpose + cast 3 weights [in][out] -> [out][in] bf16 (z selects) ----------
__global__ void k_transpose_cast(const float* __restrict__ Wk, const float* __restrict__ Wv,
                                 const float* __restrict__ Wo,
                                 unsigned short* __restrict__ Tk, unsigned short* __restrict__ Tv,
                                 unsigned short* __restrict__ To){
  __shared__ float tile[64][65];
  const int z = blockIdx.z;
  const float* W = (z == 0) ? Wk : (z == 1) ? Wv : Wo;
  unsigned short* WT = (z == 0) ? Tk : (z == 1) ? Tv : To;
  const int tid = threadIdx.x;
  const int bi = blockIdx.y * 64;
  const int bo = blockIdx.x * 64;
  #pragma unroll
  for (int it = 0; it < 16; ++it){
    int f = it*256 + tid;
    int r = f >> 6, c = f & 63;
    tile[r][c] = W[(size_t)(bi + r) * DIM + bo + c];
  }
  __syncthreads();
  #pragma unroll
  for (int it = 0; it < 16; ++it){
    int f = it*256 + tid;
    int r = f >> 6, c = f & 63;
    WT[(size_t)(bo + r) * DIM + bi + c] = f2bf(tile[c][r]);
  }
}

// ---------------- precompute ewb[h][t][s] = (s<=t) ? bf16(exp(w_aft)) : 0 ----------------
__global__ void k_ew(const float* __restrict__ waft, unsigned short* __restrict__ ewb){
  const int t = blockIdx.x;
  const int h = blockIdx.y;
  const float* src = waft + ((size_t)h*SEQ + t) * SEQ;
  unsigned short* dst = ewb + ((size_t)h*SEQ + t) * SEQ;
  const int smax4 = ((t & ~127) + 128) >> 2;
  for (int i = threadIdx.x; i < smax4; i += blockDim.x){
    const float4 w4 = reinterpret_cast<const float4*>(src)[i];
    const int s = i * 4;
    ushort4 o;
    o.x = (s+0 <= t) ? f2bf(__expf(w4.x)) : (unsigned short)0;
    o.y = (s+1 <= t) ? f2bf(__expf(w4.y)) : (unsigned short)0;
    o.z = (s+2 <= t) ? f2bf(__expf(w4.z)) : (unsigned short)0;
    o.w = (s+3 <= t) ? f2bf(__expf(w4.w)) : (unsigned short)0;
    reinterpret_cast<ushort4*>(dst)[i] = o;
  }
}

// ---------------- fused K/V projection GEMM (BK=32, counted-vmcnt dbuf) ----------------
__global__ __launch_bounds__(256) void k_proj(
    const unsigned short* __restrict__ xb,
    const unsigned short* __restrict__ wkt,
    const unsigned short* __restrict__ wvt,
    const float* __restrict__ bk,
    const float* __restrict__ bv,
    unsigned short* __restrict__ ekb)
{
  __shared__ unsigned short Al[2][128*32];
  __shared__ unsigned short Bkl[2][128*32];
  __shared__ unsigned short Bvl[2][128*32];
  const int tid  = threadIdx.x;
  const int lane = tid & 63;
  const int wr   = tid >> 7;
  const int wc   = (tid >> 6) & 1;
  const int D    = blockIdx.x;
  const int row0 = ((D & 7) * 8 + (D >> 6)) * 128;
  const int col0 = ((D >> 3) & 7) * 128;

  f32x4 acck[4][4] = {};
  f32x4 accv[4][4] = {};

  // prologue: issue kt=0 stage into buf 0 (no wait)
  #pragma unroll
  for (int it = 0; it < 2; ++it){
    const int o = it*4096 + tid*16;
    const int r = o >> 6;
    const int k = (o & 63) >> 1;
    gld_lds16(xb  + (size_t)(row0 + r)*DIM + k, (char*)&Al[0][0]  + o);
    gld_lds16(wkt + (size_t)(col0 + r)*DIM + k, (char*)&Bkl[0][0] + o);
    gld_lds16(wvt + (size_t)(col0 + r)*DIM + k, (char*)&Bvl[0][0] + o);
  }

  int cur = 0;
  for (int kt = 0; kt < DIM/32; ++kt){
    if (kt + 1 < DIM/32){
      const int kbase = (kt + 1) * 32;
      #pragma unroll
      for (int it = 0; it < 2; ++it){
        const int o = it*4096 + tid*16;
        const int r = o >> 6;
        const int k = (o & 63) >> 1;
        gld_lds16(xb  + (size_t)(row0 + r)*DIM + kbase + k, (char*)&Al[cur^1][0]  + o);
        gld_lds16(wkt + (size_t)(col0 + r)*DIM + kbase + k, (char*)&Bkl[cur^1][0] + o);
        gld_lds16(wvt + (size_t)(col0 + r)*DIM + kbase + k, (char*)&Bvl[cur^1][0] + o);
      }
      VMCNT(6);          // prev step's 6 landed (mine); barrier certifies everyone's
    } else {
      VMCNT(0);
    }
    SCHED0();
    SBAR();
    SCHED0();
    const int k0 = (lane >> 4) << 3;
    bf16x8 af[4], bkf[4], bvf[4];
    #pragma unroll
    for (int i = 0; i < 4; ++i)
      af[i] = *reinterpret_cast<const bf16x8*>(&Al[cur][(wr*64 + i*16 + (lane&15))*32 + k0]);
    #pragma unroll
    for (int j = 0; j < 4; ++j){
      bkf[j] = *reinterpret_cast<const bf16x8*>(&Bkl[cur][(wc*64 + j*16 + (lane&15))*32 + k0]);
      bvf[j] = *reinterpret_cast<const bf16x8*>(&Bvl[cur][(wc*64 + j*16 + (lane&15))*32 + k0]);
    }
    #pragma unroll
    for (int i = 0; i < 4; ++i)
      #pragma unroll
      for (int j = 0; j < 4; ++j){
        acck[i][j] = __builtin_amdgcn_mfma_f32_16x16x32_bf16(af[i], bkf[j], acck[i][j], 0, 0, 0);
        accv[i][j] = __builtin_amdgcn_mfma_f32_16x16x32_bf16(af[i], bvf[j], accv[i][j], 0, 0, 0);
      }
    SCHED0();
    SBAR();             // reads of buf[cur] done before next step overwrites buf[cur^1]... and buf[cur] next-next
    cur ^= 1;
  }

  // epilogue: packed ushort4 stores (4 consecutive s at fixed d)
  #pragma unroll
  for (int j = 0; j < 4; ++j){
    const int c = col0 + wc*64 + j*16 + (lane & 15);
    const int h = c >> 7;
    const int d = c & 127;
    const float bkc = bk[c];
    const float bvc = bv[c];
    #pragma unroll
    for (int i = 0; i < 4; ++i){
      const int r = row0 + wr*64 + i*16 + ((lane>>4)<<2);
      const int n = r >> 11;
      const int s = r & 2047;
      ushort4 pk, pv;
      #pragma unroll
      for (int jj = 0; jj < 4; ++jj){
        const float kval = acck[i][j][jj] + bkc;
        const float vval = accv[i][j][jj] + bvc;
        const float ek  = __expf(kval);
        ((unsigned short*)&pk)[jj] = f2bf(ek);
        ((unsigned short*)&pv)[jj] = f2bf(ek * vval);
      }
      const size_t idx = ((size_t)h*1024 + n*256 + d) * SEQ + s;
      *reinterpret_cast<ushort4*>(&ekb[idx]) = pk;
      *reinterpret_cast<ushort4*>(&ekb[idx + (size_t)128*SEQ]) = pv;
    }
  }
}

// ---------------- AFT causal core (ch-split, triangle-paired, counted-vmcnt dbuf) ----------
__global__ __launch_bounds__(256) void k_core(
    const unsigned short* __restrict__ ewb,
    const unsigned short* __restrict__ ekb,
    unsigned short* __restrict__ dens,
    unsigned short* __restrict__ nums)
{
  __shared__ unsigned short Al[2][128*64];
  __shared__ unsigned short Bl[2][128*64];
  const int tid  = threadIdx.x;
  const int lane = tid & 63;
  const int wr   = tid >> 7;
  const int wc   = (tid >> 6) & 1;
  const int D  = blockIdx.x;
  const int h  = D & 7;
  const int r_ = D >> 3;
  const int p  = r_ >> 3;
  const int n  = (r_ >> 1) & 3;
  const int ch = r_ & 1;

  const unsigned short* bbase = ekb + ((size_t)h*1024 + n*256 + ch*128) * SEQ;
  unsigned short* const outp = ch ? nums : dens;

  #pragma unroll
  for (int half = 0; half < 2; ++half){
    const int tt = half ? p : (15 - p);
    const int t0 = tt * 128;
    const int nst = 2*tt + 2;
    const unsigned short* abase = ewb + ((size_t)h*SEQ + t0) * SEQ;

    f32x4 acc[4][4] = {};

    // prologue: issue s-tile 0 into buf 0 (no wait)
    #pragma unroll
    for (int it = 0; it < 4; ++it){
      const int o = it*4096 + tid*16;
      const int r = o >> 7;
      const int k = (o & 127) >> 1;
      gld_lds16(abase + (size_t)r*SEQ + k, (char*)&Al[0][0] + o);
      gld_lds16(bbase + (size_t)r*SEQ + k, (char*)&Bl[0][0] + o);
    }

    int cur = 0;
    for (int st = 0; st < nst; ++st){
      if (st + 1 < nst){
        const int s0 = (st + 1) * 64;
        #pragma unroll
        for (int it = 0; it < 4; ++it){
          const int o = it*4096 + tid*16;
          const int r = o >> 7;
          const int k = (o & 127) >> 1;
          gld_lds16(abase + (size_t)r*SEQ + s0 + k, (char*)&Al[cur^1][0] + o);
          gld_lds16(bbase + (size_t)r*SEQ + s0 + k, (char*)&Bl[cur^1][0] + o);
        }
        VMCNT(8);
      } else {
        VMCNT(0);
      }
      SCHED0();
      SBAR();
      SCHED0();
      #pragma unroll
      for (int ks = 0; ks < 2; ++ks){
        const int k0 = ks*32 + ((lane >> 4) << 3);
        bf16x8 af[4], bfr[4];
        #pragma unroll
        for (int i = 0; i < 4; ++i)
          af[i] = *reinterpret_cast<const bf16x8*>(&Al[cur][(wr*64 + i*16 + (lane&15))*64 + k0]);
        #pragma unroll
        for (int j = 0; j < 4; ++j)
          bfr[j] = *reinterpret_cast<const bf16x8*>(&Bl[cur][(wc*64 + j*16 + (lane&15))*64 + k0]);
        #pragma unroll
        for (int i = 0; i < 4; ++i)
          #pragma unroll
          for (int j = 0; j < 4; ++j)
            acc[i][j] = __builtin_amdgcn_mfma_f32_16x16x32_bf16(af[i], bfr[j], acc[i][j], 0, 0, 0);
      }
      SCHED0();
      SBAR();
      cur ^= 1;
    }

    #pragma unroll
    for (int j = 0; j < 4; ++j){
      const int d = wc*64 + j*16 + (lane & 15);
      #pragma unroll
      for (int i = 0; i < 4; ++i){
        #pragma unroll
        for (int jj = 0; jj < 4; ++jj){
          const int t = t0 + wr*64 + i*16 + ((lane>>4)<<2) + jj;
          outp[((size_t)n*SEQ + t)*DIM + h*HD + d] = f2bf(acc[i][j][jj]);
        }
      }
    }
    __syncthreads();
  }
}

// ---------------- aft = num/den (bf16 in), cast bf16 ----------------
__global__ void k_div(const unsigned short* __restrict__ nums, const unsigned short* __restrict__ dens,
                      unsigned short* __restrict__ aftb, int n8){
  int i = blockIdx.x * blockDim.x + threadIdx.x;
  if (i >= n8) return;
  ushort4 nu0 = reinterpret_cast<const ushort4*>(nums)[2*i];
  ushort4 nu1 = reinterpret_cast<const ushort4*>(nums)[2*i+1];
  ushort4 de0 = reinterpret_cast<const ushort4*>(dens)[2*i];
  ushort4 de1 = reinterpret_cast<const ushort4*>(dens)[2*i+1];
  ushort4 o0, o1;
  o0.x = f2bf(bf2f(nu0.x)/bf2f(de0.x)); o0.y = f2bf(bf2f(nu0.y)/bf2f(de0.y));
  o0.z = f2bf(bf2f(nu0.z)/bf2f(de0.z)); o0.w = f2bf(bf2f(nu0.w)/bf2f(de0.w));
  o1.x = f2bf(bf2f(nu1.x)/bf2f(de1.x)); o1.y = f2bf(bf2f(nu1.y)/bf2f(de1.y));
  o1.z = f2bf(bf2f(nu1.z)/bf2f(de1.z)); o1.w = f2bf(bf2f(nu1.w)/bf2f(de1.w));
  reinterpret_cast<ushort4*>(aftb)[2*i]   = o0;
  reinterpret_cast<ushort4*>(aftb)[2*i+1] = o1;
}

// ---------------- output projection GEMM + bias (counted-vmcnt dbuf) ----------------
__global__ __launch_bounds__(256) void k_out(
    const unsigned short* __restrict__ aftb,
    const unsigned short* __restrict__ wot,
    const float* __restrict__ bo,
    float* __restrict__ out)
{
  __shared__ unsigned short Al[2][128*64];
  __shared__ unsigned short Bl[2][128*64];
  const int tid  = threadIdx.x;
  const int lane = tid & 63;
  const int wr   = tid >> 7;
  const int wc   = (tid >> 6) & 1;
  const int D    = blockIdx.x;
  const int row0 = ((D & 7) * 8 + (D >> 6)) * 128;
  const int col0 = ((D >> 3) & 7) * 128;

  f32x4 acc[4][4] = {};

  #pragma unroll
  for (int it = 0; it < 4; ++it){
    const int o = it*4096 + tid*16;
    const int r = o >> 7;
    const int k = (o & 127) >> 1;
    gld_lds16(aftb + (size_t)(row0 + r)*DIM + k, (char*)&Al[0][0] + o);
    gld_lds16(wot  + (size_t)(col0 + r)*DIM + k, (char*)&Bl[0][0] + o);
  }

  int cur = 0;
  for (int kt = 0; kt < DIM/64; ++kt){
    if (kt + 1 < DIM/64){
      const int kbase = (kt + 1) * 64;
      #pragma unroll
      for (int it = 0; it < 4; ++it){
        const int o = it*4096 + tid*16;
        const int r = o >> 7;
        const int k = (o & 127) >> 1;
        gld_lds16(aftb + (size_t)(row0 + r)*DIM + kbase + k, (char*)&Al[cur^1][0] + o);
        gld_lds16(wot  + (size_t)(col0 + r)*DIM + kbase + k, (char*)&Bl[cur^1][0] + o);
      }
      VMCNT(8);
    } else {
      VMCNT(0);
    }
    SCHED0();
    SBAR();
    SCHED0();
    #pragma unroll
    for (int ks = 0; ks < 2; ++ks){
      const int k0 = ks*32 + ((lane >> 4) << 3);
      bf16x8 af[4], bfr[4];
      #pragma unroll
      for (int i = 0; i < 4; ++i)
        af[i] = *reinterpret_cast<const bf16x8*>(&Al[cur][(wr*64 + i*16 + (lane&15))*64 + k0]);
      #pragma unroll
      for (int j = 0; j < 4; ++j)
        bfr[j] = *reinterpret_cast<const bf16x8*>(&Bl[cur][(wc*64 + j*16 + (lane&15))*64 + k0]);
      #pragma unroll
      for (int i = 0; i < 4; ++i)
        #pragma unroll
        for (int j = 0; j < 4; ++j)
          acc[i][j] = __builtin_amdgcn_mfma_f32_16x16x32_bf16(af[i], bfr[j], acc[i][j], 0, 0, 0);
    }
    SCHED0();
    SBAR();
    cur ^= 1;
  }

  #pragma unroll
  for (int j = 0; j < 4; ++j){
    const int c = col0 + wc*64 + j*16 + (lane & 15);
    const float boc = bo[c];
    #pragma unroll
    for (int i = 0; i < 4; ++i){
      #pragma unroll
      for (int jj = 0; jj < 4; ++jj){
        const int r = row0 + wr*64 + i*16 + ((lane>>4)<<2) + jj;
        out[(size_t)r*DIM + c] = acc[i][j][jj] + boc;
      }
    }
  }
}

extern "C" void kernel_launch(void* const* d_in, const int* in_sizes, int n_in,
                              void* d_out, int out_size, void* d_ws, size_t ws_size,
                              hipStream_t stream){
  const float* x    = (const float*)d_in[0];
  const float* Wk   = (const float*)d_in[1];
  const float* bk   = (const float*)d_in[2];
  const float* Wv   = (const float*)d_in[3];
  const float* bv   = (const float*)d_in[4];
  const float* waft = (const float*)d_in[5];
  const float* Wo   = (const float*)d_in[6];
  const float* bo   = (const float*)d_in[7];
  float* out = (float*)d_out;

  char* w = (char*)d_ws;
  unsigned short* xb   = (unsigned short*)w; w += (size_t)ROWS*DIM*2;       // 16 MB
  unsigned short* wkt  = (unsigned short*)w; w += (size_t)DIM*DIM*2;        // 2 MB
  unsigned short* wvt  = (unsigned short*)w; w += (size_t)DIM*DIM*2;        // 2 MB
  unsigned short* wot  = (unsigned short*)w; w += (size_t)DIM*DIM*2;        // 2 MB
  unsigned short* ekb  = (unsigned short*)w; w += (size_t)HEADS*1024*SEQ*2; // 32 MB
  unsigned short* dens = (unsigned short*)w; w += (size_t)ROWS*DIM*2;       // 16 MB
  unsigned short* nums = (unsigned short*)w; w += (size_t)ROWS*DIM*2;       // 16 MB
  unsigned short* aftb = (unsigned short*)w; w += (size_t)ROWS*DIM*2;       // 16 MB
  unsigned short* ewb  = (unsigned short*)w; w += (size_t)HEADS*SEQ*SEQ*2;  // 64 MB

  k_cast<<<ROWS*DIM/4/256, 256, 0, stream>>>(x, xb, ROWS*DIM/4);
  k_transpose_cast<<<dim3(16,16,3), 256, 0, stream>>>(Wk, Wv, Wo, wkt, wvt, wot);
  k_ew<<<dim3(SEQ, HEADS), 256, 0, stream>>>(waft, ewb);
  k_proj<<<512, 256, 0, stream>>>(xb, wkt, wvt, bk, bv, ekb);
  k_core<<<512, 256, 0, stream>>>(ewb, ekb, dens, nums);
  k_div<<<ROWS*DIM/8/256, 256, 0, stream>>>(nums, dens, aftb, ROWS*DIM/8);
  k_out<<<512, 256, 0, stream>>>(aftb, wot, bo, out);
}